// Round 2
// baseline (358.671 us; speedup 1.0000x reference)
//
#include <hip/hip_runtime.h>
#include <hip/hip_bf16.h>

// Problem constants
#define BB   4096
#define INW  1024
#define HH   1024
#define KIN  2048      // IN + H
#define NG   5120      // 3H + 2H
#define KH   32        // inner hidden
#define FPG  10        // 16-col fragments per 160-col gate-group
#define NTG  32        // number of gate-groups (= H/32)

typedef __bf16 bf16;
typedef __bf16 bf16x4 __attribute__((ext_vector_type(4)));
typedef __bf16 bf16x8 __attribute__((ext_vector_type(8)));
typedef float  floatx4 __attribute__((ext_vector_type(4)));

#define GLD16(gp, lp)                                                          \
  __builtin_amdgcn_global_load_lds(                                            \
      (__attribute__((address_space(1))) const void*)(gp),                     \
      (__attribute__((address_space(3))) void*)(lp), 16, 0, 0)

// ---------------------------------------------------------------------------
// 1. prep. Two block-level paths:
//    comb blocks: concat+cast x|h_prev, 32B read / 16B write per thread.
//    Wb blocks:   gate-permuted MFMA-fragment shuffle of Wg,Wc with
//      SEQUENTIAL row reads (256 threads x 32B = one full 8KB row per pass;
//      the old per-thread gather read 128B runs at 8KB stride -> DRAM channel
//      serialization, ~1.1 TB/s). Chunk layout reordered to [nt][f][kk][lane]
//      so one block owns a (nt,f) 16-row panel and its contiguous 64KB output
//      window. chunk = ((nt*10+f)*64 + kk)*64 + (kq*16 + s) holds
//      B[hcol = nt*32 + (f/5)*16 + s, gate f%5][k = kk*32 + kq*8 .. +7].
// ---------------------------------------------------------------------------
#define NCB  4096      // comb blocks: BB*KIN/8 threads / 256
#define NWB  1280      // Wb blocks: 32 nt x 10 f x 4 row-quarters

__global__ __launch_bounds__(256) void prep(
    const float* __restrict__ x, const float* __restrict__ h,
    const float* __restrict__ Wg, const float* __restrict__ Wc,
    bf16* __restrict__ comb, bf16* __restrict__ Wb) {
  int tid = threadIdx.x;
  if (blockIdx.x < NCB) {              // ---- comb: concat + cast ----
    int e = (blockIdx.x * 256 + tid) * 8;
    int b = e >> 11;          // / KIN
    int c = e & (KIN - 1);
    const float* src = (c < INW) ? (x + (size_t)b * INW + c)
                                 : (h + (size_t)b * HH + (c - INW));
    float4 v0 = *(const float4*)src;
    float4 v1 = *(const float4*)(src + 4);
    bf16x8 ov;
    ov[0] = (bf16)v0.x; ov[1] = (bf16)v0.y; ov[2] = (bf16)v0.z; ov[3] = (bf16)v0.w;
    ov[4] = (bf16)v1.x; ov[5] = (bf16)v1.y; ov[6] = (bf16)v1.z; ov[7] = (bf16)v1.w;
    *(bf16x8*)(comb + e) = ov;
  } else {                             // ---- Wb: sequential-row shuffle ----
    int w   = blockIdx.x - NCB;        // [0, 1280)
    int nt  = w / 40;
    int rem = w - nt * 40;
    int f   = rem >> 2;                // fragment slot 0..9
    int rp  = rem & 3;                 // row-quarter 0..3
    int q   = f / 5;
    int g   = f - q * 5;               // gate: 0=i 1=f 2=o 3=p0 4=p1
    int kk  = tid >> 2;                // k-chunk of 32
    int kq  = tid & 3;                 // k-quad within chunk
    size_t wbase = ((size_t)(nt * FPG + f) * 64 + kk) * 64 + kq * 16;
#pragma unroll
    for (int r4 = 0; r4 < 4; ++r4) {
      int s    = rp * 4 + r4;          // row-in-fragment 0..15
      int hcol = nt * 32 + q * 16 + s;
      const float* src = (g < 3)
          ? (Wg + (size_t)(g * HH + hcol) * KIN + tid * 8)
          : (Wc + (size_t)(2 * hcol + (g - 3)) * KIN + tid * 8);
      float4 v0 = *(const float4*)src;
      float4 v1 = *(const float4*)(src + 4);
      bf16x8 ov;
      ov[0] = (bf16)v0.x; ov[1] = (bf16)v0.y; ov[2] = (bf16)v0.z; ov[3] = (bf16)v0.w;
      ov[4] = (bf16)v1.x; ov[5] = (bf16)v1.y; ov[6] = (bf16)v1.z; ov[7] = (bf16)v1.w;
      *(bf16x8*)(Wb + (wbase + s) * 8) = ov;
    }
  }
}

// ---------------------------------------------------------------------------
// 2. Fused GEMM + LSTM epilogue. Tile 128x160, 4 waves 2x2, BK=128.
//    R2 change vs R1: B prefetch rolled to 2-deep (bf0/bf1, 40 VGPR instead
//    of bfr[4][5]=80) + __launch_bounds__(256,3). Unified reg use drops
//    188 -> ~150, restoring 3 blocks/CU (the R1 regression: 2 blocks/CU
//    couldn't cover the pre-barrier vmcnt(0) drain; MfmaUtil 40->26).
//    ks0/ks1 fragments are issued before the barrier pair (drain covers
//    them); ks2/ks3 refills issue between k-steps, hidden by 20-MFMA groups
//    plus cross-block overlap.
// ---------------------------------------------------------------------------
#define LOADB(buf, ksl)                                                        \
  _Pragma("unroll")                                                            \
  for (int ni = 0; ni < 5; ++ni)                                               \
    buf[ni] = *(const bf16x8*)(Bq + (size_t)ni * 32768 + (size_t)(ksl) * 512);

#define MFMAS(buf, ks)                                                         \
  {                                                                            \
    bf16x8 af[4];                                                              \
    _Pragma("unroll")                                                          \
    for (int mi = 0; mi < 4; ++mi) {                                           \
      int row  = wm + mi * 16 + lr;                                            \
      int slot = ((ks) * 4 + qd) ^ lr;                                         \
      af[mi] = *(const bf16x8*)&As[(row << 7) + (slot << 3)];                  \
    }                                                                          \
    _Pragma("unroll")                                                          \
    for (int mi = 0; mi < 4; ++mi)                                             \
      _Pragma("unroll")                                                        \
      for (int ni = 0; ni < 5; ++ni)                                           \
        acc[mi][ni] = __builtin_amdgcn_mfma_f32_16x16x32_bf16(                 \
            af[mi], buf[ni], acc[mi][ni], 0, 0, 0);                            \
  }

__global__ __launch_bounds__(256, 3) void gemm_fused(
    const bf16* __restrict__ A, const bf16* __restrict__ Bm,
    const float* __restrict__ c_prev, const float* __restrict__ bg,
    const float* __restrict__ bc, const float* __restrict__ W1,
    const float* __restrict__ b1, const float* __restrict__ W2,
    const float* __restrict__ b2, float* __restrict__ h_next,
    float* __restrict__ c_next) {
  __shared__ bf16 As[128 * 128];   // 32 KB

  const int tid  = threadIdx.x;
  const int wave = tid >> 6;
  const int lane = tid & 63;

  // XCD-aware swizzle: 1024 blocks, 8 XCDs, 128 blocks/XCD (bijective).
  const int bid = blockIdx.y * gridDim.x + blockIdx.x;
  const int swz = (bid & 7) * 128 + (bid >> 3);
  const int m0  = (swz & 31) * 128;
  const int nt  = swz >> 5;

  const int wm = (wave >> 1) * 64;   // wave row origin in tile
  const int q  = wave & 1;           // wave col half: which 16 h's
  const int lr = lane & 15;
  const int qd = lane >> 4;

  // B base in [nt][f][kk][lane] chunk order, f = q*5 + ni:
  // elem = (((nt*10 + q*5 + ni)*64 + ksl)*64 + lane) * 8
  const bf16* Bq = Bm + ((size_t)(nt * FPG + q * 5) * 4096 + lane) * 8;

  floatx4 acc[4][5] = {};

  for (int kt = 0; kt < KIN / 128; ++kt) {    // 16 iterations of BK=128
    bf16x8 bf0[5], bf1[5];
    LOADB(bf0, kt * 4 + 0);
    LOADB(bf1, kt * 4 + 1);

    __syncthreads();  // prev iter's LDS reads done; drains the 10 B loads too
#pragma unroll
    for (int j = 0; j < 8; ++j) {       // A: 2048 16B slots (128 rows x 16)
      int s   = j * 256 + tid;
      int row = s >> 4;
      int c   = (s & 15) ^ (row & 15);  // XOR swizzle
      GLD16(A + (size_t)(m0 + row) * KIN + kt * 128 + c * 8,
            As + (size_t)(j * 256 + wave * 64) * 8);
    }
    __syncthreads();

    MFMAS(bf0, 0);
    LOADB(bf0, kt * 4 + 2);
    MFMAS(bf1, 1);
    LOADB(bf1, kt * 4 + 3);
    MFMAS(bf0, 2);
    MFMAS(bf1, 3);
  }

  // ---- fused epilogue: all 5 gates of (b, h) live in this lane ----
  const int h   = nt * 32 + q * 16 + lr;
  const float bgi = bg[h];
  const float bgf = bg[HH + h];
  const float bgo = bg[2 * HH + h];
  const float bc0 = bc[2 * h];
  const float bc1 = bc[2 * h + 1];
  const float gb  = b2[0];

  float p0[16], p1[16], ga[16];
#pragma unroll
  for (int mi = 0; mi < 4; ++mi)
#pragma unroll
    for (int r = 0; r < 4; ++r) {
      p0[mi * 4 + r] = acc[mi][3][r] + bc0;
      p1[mi * 4 + r] = acc[mi][4][r] + bc1;
      ga[mi * 4 + r] = gb;
    }
  // inner MLP: k-outer so the 4 uniform weight scalars stay in SGPRs
#pragma unroll
  for (int k = 0; k < KH; ++k) {
    float w0 = W1[2 * k], w1 = W1[2 * k + 1], bk = b1[k], wk = W2[k];
#pragma unroll
    for (int e = 0; e < 16; ++e) {
      float hv = fmaf(p0[e], w0, fmaf(p1[e], w1, bk));
      hv = fmaxf(hv, 0.0f);
      ga[e] = fmaf(hv, wk, ga[e]);
    }
  }

#pragma unroll
  for (int mi = 0; mi < 4; ++mi)
#pragma unroll
    for (int r = 0; r < 4; ++r) {
      int b    = m0 + wm + mi * 16 + qd * 4 + r;
      size_t o = (size_t)b * HH + h;
      float si = 1.0f / (1.0f + __expf(-(acc[mi][0][r] + bgi)));
      float sf = 1.0f / (1.0f + __expf(-(acc[mi][1][r] + bgf)));
      float so = 1.0f / (1.0f + __expf(-(acc[mi][2][r] + bgo)));
      float cn = fmaf(sf, c_prev[o], si * ga[mi * 4 + r]);
      float e2 = __expf(2.0f * cn);          // tanh(cn) = 1 - 2/(e^{2cn}+1)
      float th = 1.0f - 2.0f / (e2 + 1.0f);
      h_next[o] = so * th;
      c_next[o] = cn;
    }
}

// ---------------------------------------------------------------------------
extern "C" void kernel_launch(void* const* d_in, const int* in_sizes, int n_in,
                              void* d_out, int out_size, void* d_ws, size_t ws_size,
                              hipStream_t stream) {
  const float* x      = (const float*)d_in[0];
  const float* h_prev = (const float*)d_in[1];
  const float* c_prev = (const float*)d_in[2];
  const float* Wg     = (const float*)d_in[3];
  const float* bg     = (const float*)d_in[4];
  const float* Wc     = (const float*)d_in[5];
  const float* bc     = (const float*)d_in[6];
  const float* W1     = (const float*)d_in[7];
  const float* b1     = (const float*)d_in[8];
  const float* W2     = (const float*)d_in[9];
  const float* b2     = (const float*)d_in[10];
  float* out = (float*)d_out;

  // workspace layout
  char* ws = (char*)d_ws;
  bf16* comb = (bf16*)ws;                                    // 16 MB
  bf16* Wb   = (bf16*)(ws + (size_t)BB * KIN * 2);           // 20 MB

  // 1. prep (concat + cast + gate-permuted, sequential-read B shuffle)
  prep<<<NCB + NWB, 256, 0, stream>>>(x, h_prev, Wg, Wc, comb, Wb);

  // 2. fused GEMM + epilogue
  dim3 grid(BB / 128, NTG);
  gemm_fused<<<grid, 256, 0, stream>>>(comb, Wb, c_prev, bg, bc, W1, b1, W2,
                                       b2, out, out + (size_t)BB * HH);
}

// Round 3
// 267.749 us; speedup vs baseline: 1.3396x; 1.3396x over previous
//
#include <hip/hip_runtime.h>
#include <hip/hip_bf16.h>

// Problem constants
#define BB   4096
#define INW  1024
#define HH   1024
#define KIN  2048      // IN + H
#define NG   5120      // 3H + 2H
#define KH   32        // inner hidden
#define FPG  10        // 16-col fragments per 160-col gate-group
#define NTG  32        // number of gate-groups (= H/32)

typedef __bf16 bf16;
typedef __bf16 bf16x4 __attribute__((ext_vector_type(4)));
typedef __bf16 bf16x8 __attribute__((ext_vector_type(8)));
typedef float  floatx4 __attribute__((ext_vector_type(4)));

#define GLD16(gp, lp)                                                          \
  __builtin_amdgcn_global_load_lds(                                            \
      (__attribute__((address_space(1))) const void*)(gp),                     \
      (__attribute__((address_space(3))) void*)(lp), 16, 0, 0)

// ---------------------------------------------------------------------------
// 1. prep (unchanged from R2 — sequential-row B shuffle, coalesced comb).
//    Wb chunk layout [nt][f][kk][lane]: chunk = ((nt*10+f)*64 + kk)*64 +
//    (kq*16 + s) holds B[hcol = nt*32 + (f/5)*16 + s, gate f%5]
//    [k = kk*32 + kq*8 .. +7].
// ---------------------------------------------------------------------------
#define NCB  4096      // comb blocks: BB*KIN/8 threads / 256
#define NWB  1280      // Wb blocks: 32 nt x 10 f x 4 row-quarters

__global__ __launch_bounds__(256) void prep(
    const float* __restrict__ x, const float* __restrict__ h,
    const float* __restrict__ Wg, const float* __restrict__ Wc,
    bf16* __restrict__ comb, bf16* __restrict__ Wb) {
  int tid = threadIdx.x;
  if (blockIdx.x < NCB) {              // ---- comb: concat + cast ----
    int e = (blockIdx.x * 256 + tid) * 8;
    int b = e >> 11;          // / KIN
    int c = e & (KIN - 1);
    const float* src = (c < INW) ? (x + (size_t)b * INW + c)
                                 : (h + (size_t)b * HH + (c - INW));
    float4 v0 = *(const float4*)src;
    float4 v1 = *(const float4*)(src + 4);
    bf16x8 ov;
    ov[0] = (bf16)v0.x; ov[1] = (bf16)v0.y; ov[2] = (bf16)v0.z; ov[3] = (bf16)v0.w;
    ov[4] = (bf16)v1.x; ov[5] = (bf16)v1.y; ov[6] = (bf16)v1.z; ov[7] = (bf16)v1.w;
    *(bf16x8*)(comb + e) = ov;
  } else {                             // ---- Wb: sequential-row shuffle ----
    int w   = blockIdx.x - NCB;        // [0, 1280)
    int nt  = w / 40;
    int rem = w - nt * 40;
    int f   = rem >> 2;                // fragment slot 0..9
    int rp  = rem & 3;                 // row-quarter 0..3
    int q   = f / 5;
    int g   = f - q * 5;               // gate: 0=i 1=f 2=o 3=p0 4=p1
    int kk  = tid >> 2;                // k-chunk of 32
    int kq  = tid & 3;                 // k-quad within chunk
    size_t wbase = ((size_t)(nt * FPG + f) * 64 + kk) * 64 + kq * 16;
#pragma unroll
    for (int r4 = 0; r4 < 4; ++r4) {
      int s    = rp * 4 + r4;          // row-in-fragment 0..15
      int hcol = nt * 32 + q * 16 + s;
      const float* src = (g < 3)
          ? (Wg + (size_t)(g * HH + hcol) * KIN + tid * 8)
          : (Wc + (size_t)(2 * hcol + (g - 3)) * KIN + tid * 8);
      float4 v0 = *(const float4*)src;
      float4 v1 = *(const float4*)(src + 4);
      bf16x8 ov;
      ov[0] = (bf16)v0.x; ov[1] = (bf16)v0.y; ov[2] = (bf16)v0.z; ov[3] = (bf16)v0.w;
      ov[4] = (bf16)v1.x; ov[5] = (bf16)v1.y; ov[6] = (bf16)v1.z; ov[7] = (bf16)v1.w;
      *(bf16x8*)(Wb + (wbase + s) * 8) = ov;
    }
  }
}

// ---------------------------------------------------------------------------
// 2. Fused GEMM + LSTM epilogue. R3: tile 64x160 (BM halved vs R1/R2).
//    acc[2][5] = 40 regs -> the R0-proven FULL-DEPTH B prefetch (bfr[4][5] =
//    80 regs, issued before the barrier pair so the structural vmcnt(0)
//    drain covers it) fits in ~148 total regs at 3 blocks/CU WITHOUT spill.
//    (R2 post-mortem: launch_bounds(256,3) + acc 80 split the file 84+84,
//    spilled ~70 regs -> WRITE_SIZE 32->111 MB, MfmaUtil 13%.)
//    4 waves as 2x2: wave owns 32 rows x 80 cols (5 gates of 16 h's).
//    LDS 16 KB single-buffered A tile, XOR-swizzled, BK=128, 2048 blocks.
// ---------------------------------------------------------------------------
__global__ __launch_bounds__(256, 3) void gemm_fused(
    const bf16* __restrict__ A, const bf16* __restrict__ Bm,
    const float* __restrict__ c_prev, const float* __restrict__ bg,
    const float* __restrict__ bc, const float* __restrict__ W1,
    const float* __restrict__ b1, const float* __restrict__ W2,
    const float* __restrict__ b2, float* __restrict__ h_next,
    float* __restrict__ c_next) {
  __shared__ bf16 As[64 * 128];    // 16 KB

  const int tid  = threadIdx.x;
  const int wave = tid >> 6;
  const int lane = tid & 63;

  // XCD-aware swizzle: 2048 blocks, 8 XCDs, 256 blocks/XCD (bijective).
  // m varies fastest within an XCD -> the 640 KB B panel stays L2-hot.
  const int bid = blockIdx.y * gridDim.x + blockIdx.x;
  const int swz = (bid & 7) * 256 + (bid >> 3);
  const int m0  = (swz & 63) * 64;
  const int nt  = swz >> 6;

  const int wm = (wave >> 1) * 32;   // wave row origin in tile
  const int q  = wave & 1;           // wave col half: which 16 h's
  const int lr = lane & 15;
  const int qd = lane >> 4;

  // B base in [nt][f][kk][lane] chunk order, f = q*5 + ni:
  // elem = (((nt*10 + q*5 + ni)*64 + ksl)*64 + lane) * 8
  const bf16* Bq = Bm + ((size_t)(nt * FPG + q * 5) * 4096 + lane) * 8;

  floatx4 acc[2][5] = {};

  for (int kt = 0; kt < KIN / 128; ++kt) {    // 16 iterations of BK=128
    // Full-depth B prefetch: 20 x 16B loads issued BEFORE the barrier pair
    // so the pre-barrier vmcnt(0) drain covers their latency (R0 pattern).
    bf16x8 bfr[4][5];
#pragma unroll
    for (int ks = 0; ks < 4; ++ks)
#pragma unroll
      for (int ni = 0; ni < 5; ++ni)
        bfr[ks][ni] = *(const bf16x8*)(
            Bq + (size_t)ni * 32768 + (size_t)(kt * 4 + ks) * 512);

    __syncthreads();  // prev iter's LDS reads done before overwrite
#pragma unroll
    for (int j = 0; j < 4; ++j) {       // A: 1024 16B slots (64 rows x 16)
      int s   = j * 256 + tid;
      int row = s >> 4;
      int c   = (s & 15) ^ (row & 15);  // XOR swizzle
      GLD16(A + (size_t)(m0 + row) * KIN + kt * 128 + c * 8,
            As + (size_t)(j * 256 + wave * 64) * 8);
    }
    __syncthreads();

#pragma unroll
    for (int ks = 0; ks < 4; ++ks) {    // 4 k-steps of 32
      bf16x8 af[2];
#pragma unroll
      for (int mi = 0; mi < 2; ++mi) {
        int row  = wm + mi * 16 + lr;
        int slot = (ks * 4 + qd) ^ lr;  // row&15 == lr
        af[mi] = *(const bf16x8*)&As[(row << 7) + (slot << 3)];
      }
#pragma unroll
      for (int mi = 0; mi < 2; ++mi)
#pragma unroll
        for (int ni = 0; ni < 5; ++ni)
          acc[mi][ni] = __builtin_amdgcn_mfma_f32_16x16x32_bf16(
              af[mi], bfr[ks][ni], acc[mi][ni], 0, 0, 0);
    }
  }

  // ---- fused epilogue: all 5 gates of (b, h) live in this lane ----
  const int h   = nt * 32 + q * 16 + lr;
  const float bgi = bg[h];
  const float bgf = bg[HH + h];
  const float bgo = bg[2 * HH + h];
  const float bc0 = bc[2 * h];
  const float bc1 = bc[2 * h + 1];
  const float gb  = b2[0];

  float p0[8], p1[8], ga[8];
#pragma unroll
  for (int mi = 0; mi < 2; ++mi)
#pragma unroll
    for (int r = 0; r < 4; ++r) {
      p0[mi * 4 + r] = acc[mi][3][r] + bc0;
      p1[mi * 4 + r] = acc[mi][4][r] + bc1;
      ga[mi * 4 + r] = gb;
    }
  // inner MLP: k-outer so the 4 uniform weight scalars stay in SGPRs
#pragma unroll
  for (int k = 0; k < KH; ++k) {
    float w0 = W1[2 * k], w1 = W1[2 * k + 1], bk = b1[k], wk = W2[k];
#pragma unroll
    for (int e = 0; e < 8; ++e) {
      float hv = fmaf(p0[e], w0, fmaf(p1[e], w1, bk));
      hv = fmaxf(hv, 0.0f);
      ga[e] = fmaf(hv, wk, ga[e]);
    }
  }

#pragma unroll
  for (int mi = 0; mi < 2; ++mi)
#pragma unroll
    for (int r = 0; r < 4; ++r) {
      int b    = m0 + wm + mi * 16 + qd * 4 + r;
      size_t o = (size_t)b * HH + h;
      float si = 1.0f / (1.0f + __expf(-(acc[mi][0][r] + bgi)));
      float sf = 1.0f / (1.0f + __expf(-(acc[mi][1][r] + bgf)));
      float so = 1.0f / (1.0f + __expf(-(acc[mi][2][r] + bgo)));
      float cn = fmaf(sf, c_prev[o], si * ga[mi * 4 + r]);
      float e2 = __expf(2.0f * cn);          // tanh(cn) = 1 - 2/(e^{2cn}+1)
      float th = 1.0f - 2.0f / (e2 + 1.0f);
      h_next[o] = so * th;
      c_next[o] = cn;
    }
}

// ---------------------------------------------------------------------------
extern "C" void kernel_launch(void* const* d_in, const int* in_sizes, int n_in,
                              void* d_out, int out_size, void* d_ws, size_t ws_size,
                              hipStream_t stream) {
  const float* x      = (const float*)d_in[0];
  const float* h_prev = (const float*)d_in[1];
  const float* c_prev = (const float*)d_in[2];
  const float* Wg     = (const float*)d_in[3];
  const float* bg     = (const float*)d_in[4];
  const float* Wc     = (const float*)d_in[5];
  const float* bc     = (const float*)d_in[6];
  const float* W1     = (const float*)d_in[7];
  const float* b1     = (const float*)d_in[8];
  const float* W2     = (const float*)d_in[9];
  const float* b2     = (const float*)d_in[10];
  float* out = (float*)d_out;

  // workspace layout
  char* ws = (char*)d_ws;
  bf16* comb = (bf16*)ws;                                    // 16 MB
  bf16* Wb   = (bf16*)(ws + (size_t)BB * KIN * 2);           // 20 MB

  // 1. prep (concat + cast + gate-permuted, sequential-read B shuffle)
  prep<<<NCB + NWB, 256, 0, stream>>>(x, h_prev, Wg, Wc, comb, Wb);

  // 2. fused GEMM + epilogue
  dim3 grid(BB / 64, NTG);
  gemm_fused<<<grid, 256, 0, stream>>>(comb, Wb, c_prev, bg, bc, W1, b1, W2,
                                       b2, out, out + (size_t)BB * HH);
}

// Round 4
// 250.790 us; speedup vs baseline: 1.4302x; 1.0676x over previous
//
#include <hip/hip_runtime.h>
#include <hip/hip_bf16.h>

// Problem constants
#define BB   4096
#define INW  1024
#define HH   1024
#define KIN  2048      // IN + H
#define NG   5120      // 3H + 2H
#define KH   32        // inner hidden
#define FPG  10        // 16-col fragments per 160-col gate-group
#define NTG  32        // number of gate-groups (= H/32)

typedef __bf16 bf16;
typedef __bf16 bf16x4 __attribute__((ext_vector_type(4)));
typedef __bf16 bf16x8 __attribute__((ext_vector_type(8)));
typedef float  floatx4 __attribute__((ext_vector_type(4)));

#define GLD16(gp, lp)                                                          \
  __builtin_amdgcn_global_load_lds(                                            \
      (__attribute__((address_space(1))) const void*)(gp),                     \
      (__attribute__((address_space(3))) void*)(lp), 16, 0, 0)

// ---------------------------------------------------------------------------
// 1. prep (unchanged from R2/R3 — sequential-row B shuffle, coalesced comb).
//    Wb chunk layout [nt][f][kk][lane]: chunk = ((nt*10+f)*64 + kk)*64 +
//    (kq*16 + s) holds B[hcol = nt*32 + (f/5)*16 + s, gate f%5]
//    [k = kk*32 + kq*8 .. +7].
// ---------------------------------------------------------------------------
#define NCB  4096      // comb blocks: BB*KIN/8 threads / 256
#define NWB  1280      // Wb blocks: 32 nt x 10 f x 4 row-quarters

__global__ __launch_bounds__(256) void prep(
    const float* __restrict__ x, const float* __restrict__ h,
    const float* __restrict__ Wg, const float* __restrict__ Wc,
    bf16* __restrict__ comb, bf16* __restrict__ Wb) {
  int tid = threadIdx.x;
  if (blockIdx.x < NCB) {              // ---- comb: concat + cast ----
    int e = (blockIdx.x * 256 + tid) * 8;
    int b = e >> 11;          // / KIN
    int c = e & (KIN - 1);
    const float* src = (c < INW) ? (x + (size_t)b * INW + c)
                                 : (h + (size_t)b * HH + (c - INW));
    float4 v0 = *(const float4*)src;
    float4 v1 = *(const float4*)(src + 4);
    bf16x8 ov;
    ov[0] = (bf16)v0.x; ov[1] = (bf16)v0.y; ov[2] = (bf16)v0.z; ov[3] = (bf16)v0.w;
    ov[4] = (bf16)v1.x; ov[5] = (bf16)v1.y; ov[6] = (bf16)v1.z; ov[7] = (bf16)v1.w;
    *(bf16x8*)(comb + e) = ov;
  } else {                             // ---- Wb: sequential-row shuffle ----
    int w   = blockIdx.x - NCB;        // [0, 1280)
    int nt  = w / 40;
    int rem = w - nt * 40;
    int f   = rem >> 2;                // fragment slot 0..9
    int rp  = rem & 3;                 // row-quarter 0..3
    int q   = f / 5;
    int g   = f - q * 5;               // gate: 0=i 1=f 2=o 3=p0 4=p1
    int kk  = tid >> 2;                // k-chunk of 32
    int kq  = tid & 3;                 // k-quad within chunk
    size_t wbase = ((size_t)(nt * FPG + f) * 64 + kk) * 64 + kq * 16;
#pragma unroll
    for (int r4 = 0; r4 < 4; ++r4) {
      int s    = rp * 4 + r4;          // row-in-fragment 0..15
      int hcol = nt * 32 + q * 16 + s;
      const float* src = (g < 3)
          ? (Wg + (size_t)(g * HH + hcol) * KIN + tid * 8)
          : (Wc + (size_t)(2 * hcol + (g - 3)) * KIN + tid * 8);
      float4 v0 = *(const float4*)src;
      float4 v1 = *(const float4*)(src + 4);
      bf16x8 ov;
      ov[0] = (bf16)v0.x; ov[1] = (bf16)v0.y; ov[2] = (bf16)v0.z; ov[3] = (bf16)v0.w;
      ov[4] = (bf16)v1.x; ov[5] = (bf16)v1.y; ov[6] = (bf16)v1.z; ov[7] = (bf16)v1.w;
      *(bf16x8*)(Wb + (wbase + s) * 8) = ov;
    }
  }
}

// ---------------------------------------------------------------------------
// 2. Fused GEMM + LSTM epilogue. R4: tile back to 128x160 (restores A-side
//    arithmetic intensity — R3's BM=64 doubled FETCH to 285 MB and went
//    memory-bound), with B staged through LDS via global_load_lds so the
//    staging costs ZERO VGPRs (resolves the R1-occupancy / R2-spill /
//    R3-refetch triangle). BK=64: LDS = A 16 KB (XOR-swizzled) + B 20 KB
//    (linear chunk order = the gload_lds wave-uniform+lane*16 pattern;
//    ds_read at lane*16B is conflict-free). Regs: acc[4][5]=80 AGPR +
//    af 16 + bfr 20 + addr ~25 ≈ 140 -> fits (256,3) without spill.
//    Per barrier pair: 9 GLD16/thread staged, 2 ks-steps x 20 MFMA.
// ---------------------------------------------------------------------------
__global__ __launch_bounds__(256, 3) void gemm_fused(
    const bf16* __restrict__ A, const bf16* __restrict__ Bm,
    const float* __restrict__ c_prev, const float* __restrict__ bg,
    const float* __restrict__ bc, const float* __restrict__ W1,
    const float* __restrict__ b1, const float* __restrict__ W2,
    const float* __restrict__ b2, float* __restrict__ h_next,
    float* __restrict__ c_next) {
  __shared__ bf16 As[128 * 64];    // 16 KB
  __shared__ bf16 Bs[20 * 512];    // 20 KB: 20 chunks of 1 KB (64 x 16B)

  const int tid  = threadIdx.x;
  const int wave = tid >> 6;
  const int lane = tid & 63;

  // XCD-aware swizzle: 1024 blocks, 8 XCDs, 128 blocks/XCD (bijective).
  // m varies fastest within an XCD -> the 640 KB B panel stays L2-hot.
  const int bid = blockIdx.y * gridDim.x + blockIdx.x;
  const int swz = (bid & 7) * 128 + (bid >> 3);
  const int m0  = (swz & 31) * 128;
  const int nt  = swz >> 5;

  const int wm = (wave >> 1) * 64;   // wave row origin in tile
  const int q  = wave & 1;           // wave col half: which 16 h's
  const int lr = lane & 15;
  const int qd = lane >> 4;

  floatx4 acc[4][5] = {};

  for (int kt = 0; kt < KIN / 64; ++kt) {     // 32 iterations of BK=64
    __syncthreads();  // prev iter's LDS reads done before overwrite

    // ---- stage A: 1024 slots (128 rows x 8 chunks), XOR-swizzled ----
#pragma unroll
    for (int j = 0; j < 4; ++j) {
      int s   = j * 256 + tid;
      int row = s >> 3;
      int c   = (s & 7) ^ (row & 7);
      GLD16(A + (size_t)(m0 + row) * KIN + kt * 64 + c * 8,
            As + (size_t)(j * 256 + wave * 64) * 8);
    }
    // ---- stage B: 20 chunks of 1 KB, linear (chunk = f*2 + ks) ----
#pragma unroll
    for (int j = 0; j < 5; ++j) {
      int c20 = j * 4 + wave;          // 0..19, wave-uniform
      int f   = c20 >> 1;
      int ks  = c20 & 1;
      size_t gchunk = (size_t)(nt * FPG + f) * 64 + (kt * 2 + ks);
      GLD16(Bm + (gchunk * 64 + lane) * 8,
            Bs + (size_t)(j * 256 + wave * 64) * 8);
    }
    __syncthreads();

#pragma unroll
    for (int ks = 0; ks < 2; ++ks) {    // 2 k-steps of 32
      bf16x8 af[4];
#pragma unroll
      for (int mi = 0; mi < 4; ++mi) {
        int row  = wm + mi * 16 + lr;
        int slot = (ks * 4 + qd) ^ (lr & 7);
        af[mi] = *(const bf16x8*)&As[(row << 6) + (slot << 3)];
      }
      bf16x8 bfr[5];
#pragma unroll
      for (int ni = 0; ni < 5; ++ni) {
        int chunk = ((q * 5 + ni) << 1) + ks;
        bfr[ni] = *(const bf16x8*)&Bs[(chunk << 9) + (lane << 3)];
      }
#pragma unroll
      for (int mi = 0; mi < 4; ++mi)
#pragma unroll
        for (int ni = 0; ni < 5; ++ni)
          acc[mi][ni] = __builtin_amdgcn_mfma_f32_16x16x32_bf16(
              af[mi], bfr[ni], acc[mi][ni], 0, 0, 0);
    }
  }

  // ---- fused epilogue: all 5 gates of (b, h) live in this lane ----
  const int h   = nt * 32 + q * 16 + lr;
  const float bgi = bg[h];
  const float bgf = bg[HH + h];
  const float bgo = bg[2 * HH + h];
  const float bc0 = bc[2 * h];
  const float bc1 = bc[2 * h + 1];
  const float gb  = b2[0];

  float p0[16], p1[16], ga[16];
#pragma unroll
  for (int mi = 0; mi < 4; ++mi)
#pragma unroll
    for (int r = 0; r < 4; ++r) {
      p0[mi * 4 + r] = acc[mi][3][r] + bc0;
      p1[mi * 4 + r] = acc[mi][4][r] + bc1;
      ga[mi * 4 + r] = gb;
    }
  // inner MLP: k-outer so the 4 uniform weight scalars stay in SGPRs
#pragma unroll
  for (int k = 0; k < KH; ++k) {
    float w0 = W1[2 * k], w1 = W1[2 * k + 1], bk = b1[k], wk = W2[k];
#pragma unroll
    for (int e = 0; e < 16; ++e) {
      float hv = fmaf(p0[e], w0, fmaf(p1[e], w1, bk));
      hv = fmaxf(hv, 0.0f);
      ga[e] = fmaf(hv, wk, ga[e]);
    }
  }

#pragma unroll
  for (int mi = 0; mi < 4; ++mi)
#pragma unroll
    for (int r = 0; r < 4; ++r) {
      int b    = m0 + wm + mi * 16 + qd * 4 + r;
      size_t o = (size_t)b * HH + h;
      float si = 1.0f / (1.0f + __expf(-(acc[mi][0][r] + bgi)));
      float sf = 1.0f / (1.0f + __expf(-(acc[mi][1][r] + bgf)));
      float so = 1.0f / (1.0f + __expf(-(acc[mi][2][r] + bgo)));
      float cn = fmaf(sf, c_prev[o], si * ga[mi * 4 + r]);
      float e2 = __expf(2.0f * cn);          // tanh(cn) = 1 - 2/(e^{2cn}+1)
      float th = 1.0f - 2.0f / (e2 + 1.0f);
      h_next[o] = so * th;
      c_next[o] = cn;
    }
}

// ---------------------------------------------------------------------------
extern "C" void kernel_launch(void* const* d_in, const int* in_sizes, int n_in,
                              void* d_out, int out_size, void* d_ws, size_t ws_size,
                              hipStream_t stream) {
  const float* x      = (const float*)d_in[0];
  const float* h_prev = (const float*)d_in[1];
  const float* c_prev = (const float*)d_in[2];
  const float* Wg     = (const float*)d_in[3];
  const float* bg     = (const float*)d_in[4];
  const float* Wc     = (const float*)d_in[5];
  const float* bc     = (const float*)d_in[6];
  const float* W1     = (const float*)d_in[7];
  const float* b1     = (const float*)d_in[8];
  const float* W2     = (const float*)d_in[9];
  const float* b2     = (const float*)d_in[10];
  float* out = (float*)d_out;

  // workspace layout
  char* ws = (char*)d_ws;
  bf16* comb = (bf16*)ws;                                    // 16 MB
  bf16* Wb   = (bf16*)(ws + (size_t)BB * KIN * 2);           // 20 MB

  // 1. prep (concat + cast + gate-permuted, sequential-read B shuffle)
  prep<<<NCB + NWB, 256, 0, stream>>>(x, h_prev, Wg, Wc, comb, Wb);

  // 2. fused GEMM + epilogue
  dim3 grid(BB / 128, NTG);
  gemm_fused<<<grid, 256, 0, stream>>>(comb, Wb, c_prev, bg, bc, W1, b1, W2,
                                       b2, out, out + (size_t)BB * HH);
}

// Round 5
// 246.150 us; speedup vs baseline: 1.4571x; 1.0188x over previous
//
#include <hip/hip_runtime.h>
#include <hip/hip_bf16.h>

// Problem constants
#define BB   4096
#define INW  1024
#define HH   1024
#define KIN  2048      // IN + H
#define NG   5120      // 3H + 2H
#define KH   32        // inner hidden
#define FPG  10        // 16-col fragments per 160-col gate-group
#define NTG  32        // number of gate-groups (= H/32)

typedef __bf16 bf16;
typedef __bf16 bf16x4 __attribute__((ext_vector_type(4)));
typedef __bf16 bf16x8 __attribute__((ext_vector_type(8)));
typedef float  floatx4 __attribute__((ext_vector_type(4)));

#define GLD16(gp, lp)                                                          \
  __builtin_amdgcn_global_load_lds(                                            \
      (__attribute__((address_space(1))) const void*)(gp),                     \
      (__attribute__((address_space(3))) void*)(lp), 16, 0, 0)

// ---------------------------------------------------------------------------
// 1. prep (unchanged — sequential-row B shuffle, coalesced comb).
//    Wb chunk layout [F][kk][lane] with F = nt*10+f: chunk = (F*64 + kk)*64 +
//    (kq*16 + s) holds B[hcol = nt*32 + (f/5)*16 + s, gate f%5]
//    [k = kk*32 + kq*8 .. +7].
// ---------------------------------------------------------------------------
#define NCB  4096      // comb blocks: BB*KIN/8 threads / 256
#define NWB  1280      // Wb blocks: 32 nt x 10 f x 4 row-quarters

__global__ __launch_bounds__(256) void prep(
    const float* __restrict__ x, const float* __restrict__ h,
    const float* __restrict__ Wg, const float* __restrict__ Wc,
    bf16* __restrict__ comb, bf16* __restrict__ Wb) {
  int tid = threadIdx.x;
  if (blockIdx.x < NCB) {              // ---- comb: concat + cast ----
    int e = (blockIdx.x * 256 + tid) * 8;
    int b = e >> 11;          // / KIN
    int c = e & (KIN - 1);
    const float* src = (c < INW) ? (x + (size_t)b * INW + c)
                                 : (h + (size_t)b * HH + (c - INW));
    float4 v0 = *(const float4*)src;
    float4 v1 = *(const float4*)(src + 4);
    bf16x8 ov;
    ov[0] = (bf16)v0.x; ov[1] = (bf16)v0.y; ov[2] = (bf16)v0.z; ov[3] = (bf16)v0.w;
    ov[4] = (bf16)v1.x; ov[5] = (bf16)v1.y; ov[6] = (bf16)v1.z; ov[7] = (bf16)v1.w;
    *(bf16x8*)(comb + e) = ov;
  } else {                             // ---- Wb: sequential-row shuffle ----
    int w   = blockIdx.x - NCB;        // [0, 1280)
    int nt  = w / 40;
    int rem = w - nt * 40;
    int f   = rem >> 2;                // fragment slot 0..9
    int rp  = rem & 3;                 // row-quarter 0..3
    int q   = f / 5;
    int g   = f - q * 5;               // gate: 0=i 1=f 2=o 3=p0 4=p1
    int kk  = tid >> 2;                // k-chunk of 32
    int kq  = tid & 3;                 // k-quad within chunk
    size_t wbase = ((size_t)(nt * FPG + f) * 64 + kk) * 64 + kq * 16;
#pragma unroll
    for (int r4 = 0; r4 < 4; ++r4) {
      int s    = rp * 4 + r4;          // row-in-fragment 0..15
      int hcol = nt * 32 + q * 16 + s;
      const float* src = (g < 3)
          ? (Wg + (size_t)(g * HH + hcol) * KIN + tid * 8)
          : (Wc + (size_t)(2 * hcol + (g - 3)) * KIN + tid * 8);
      float4 v0 = *(const float4*)src;
      float4 v1 = *(const float4*)(src + 4);
      bf16x8 ov;
      ov[0] = (bf16)v0.x; ov[1] = (bf16)v0.y; ov[2] = (bf16)v0.z; ov[3] = (bf16)v0.w;
      ov[4] = (bf16)v1.x; ov[5] = (bf16)v1.y; ov[6] = (bf16)v1.z; ov[7] = (bf16)v1.w;
      *(bf16x8*)(Wb + (wbase + s) * 8) = ov;
    }
  }
}

// ---------------------------------------------------------------------------
// 2. Fused GEMM + LSTM epilogue. R5: same geometry as R4 (128x160, BK=64,
//    A+B via global_load_lds) but DOUBLE-BUFFERED with the 2-phase pipeline:
//      prologue: STAGE(buf0, 0); barrier(vmcnt0)
//      iter t:   STAGE(buf^1, t+1); compute(buf, t); barrier(vmcnt0); flip
//    R4 post-mortem: loads were issued immediately before the barrier that
//    drained them -> full ~900cyc latency exposed per iteration (iteration
//    quantum ~3050cyc x 128 execs/CU = 162us, MfmaUtil 22%). Now the loads
//    for tile t+1 are in flight DURING tile t's 40-MFMA compute phase; the
//    residual drain is covered by the co-resident block.
//    LDS 2 x 36 KB = 72 KB -> 2 blocks/CU; reg budget 256/thread at
//    2 waves/SIMD -> acc 80 + af 16 + bfr 20 + addr ~25 fits, no spill.
// ---------------------------------------------------------------------------
#define ASZ  8192      // A elems per buffer (16 KB)
#define BSZ  10240     // B elems per buffer (20 KB)
#define BUF  (ASZ + BSZ)

__global__ __launch_bounds__(256, 2) void gemm_fused(
    const bf16* __restrict__ A, const bf16* __restrict__ Bm,
    const float* __restrict__ c_prev, const float* __restrict__ bg,
    const float* __restrict__ bc, const float* __restrict__ W1,
    const float* __restrict__ b1, const float* __restrict__ W2,
    const float* __restrict__ b2, float* __restrict__ h_next,
    float* __restrict__ c_next) {
  __shared__ bf16 sh[2 * BUF];     // 72 KB: two {A 16K + B 20K} buffers

  const int tid  = threadIdx.x;
  const int wave = tid >> 6;
  const int lane = tid & 63;

  // XCD-aware swizzle: 1024 blocks, 8 XCDs, 128 blocks/XCD (bijective).
  const int bid = blockIdx.y * gridDim.x + blockIdx.x;
  const int swz = (bid & 7) * 128 + (bid >> 3);
  const int m0  = (swz & 31) * 128;
  const int nt  = swz >> 5;

  const int wm = (wave >> 1) * 64;   // wave row origin in tile
  const int q  = wave & 1;           // wave col half: which 16 h's
  const int lr = lane & 15;
  const int qd = lane >> 4;

  floatx4 acc[4][5] = {};

  // Per-thread staging constants
  const int arow0 = tid >> 3;                 // A rows handled: arow0 + j*32
  const int acol  = (tid & 7);                // swizzled below per row
  const int bf20  = wave;                     // B chunks: wave + j*4

  // ---- STAGE(buf, kt): 4 A-chunks + 5 B-chunks per thread ----
#define STAGE(bb, kt)                                                          \
  {                                                                            \
    _Pragma("unroll")                                                          \
    for (int j = 0; j < 4; ++j) {                                              \
      int row = arow0 + j * 32;                                                \
      int c   = acol ^ (row & 7);                                              \
      GLD16(A + (size_t)(m0 + row) * KIN + (kt) * 64 + c * 8,                  \
            sh + (size_t)(bb) * BUF + (size_t)(j * 256 + wave * 64) * 8);      \
    }                                                                          \
    _Pragma("unroll")                                                          \
    for (int j = 0; j < 5; ++j) {                                              \
      int c20 = j * 4 + bf20;                                                  \
      int f   = c20 >> 1;                                                      \
      int ks  = c20 & 1;                                                       \
      size_t gchunk = (size_t)(nt * FPG + f) * 64 + ((kt) * 2 + ks);           \
      GLD16(Bm + (gchunk * 64 + lane) * 8,                                     \
            sh + (size_t)(bb) * BUF + ASZ +                                    \
                (size_t)(j * 256 + wave * 64) * 8);                            \
    }                                                                          \
  }

  // ---- COMPUTE(buf): 2 k-steps x 20 MFMA from buffer bb ----
#define COMPUTE(bb)                                                            \
  {                                                                            \
    const bf16* As = sh + (size_t)(bb) * BUF;                                  \
    const bf16* Bs = As + ASZ;                                                 \
    _Pragma("unroll")                                                          \
    for (int ks = 0; ks < 2; ++ks) {                                           \
      bf16x8 af[4];                                                            \
      _Pragma("unroll")                                                        \
      for (int mi = 0; mi < 4; ++mi) {                                         \
        int row  = wm + mi * 16 + lr;                                          \
        int slot = (ks * 4 + qd) ^ (lr & 7);                                   \
        af[mi] = *(const bf16x8*)&As[(row << 6) + (slot << 3)];                \
      }                                                                        \
      bf16x8 bfr[5];                                                           \
      _Pragma("unroll")                                                        \
      for (int ni = 0; ni < 5; ++ni) {                                         \
        int chunk = ((q * 5 + ni) << 1) + ks;                                  \
        bfr[ni] = *(const bf16x8*)&Bs[(chunk << 9) + (lane << 3)];             \
      }                                                                        \
      _Pragma("unroll")                                                        \
      for (int mi = 0; mi < 4; ++mi)                                           \
        _Pragma("unroll")                                                      \
        for (int ni = 0; ni < 5; ++ni)                                         \
          acc[mi][ni] = __builtin_amdgcn_mfma_f32_16x16x32_bf16(               \
              af[mi], bfr[ni], acc[mi][ni], 0, 0, 0);                          \
    }                                                                          \
  }

  // Prologue: stage tile 0, drain, barrier.
  STAGE(0, 0);
  __syncthreads();   // emits s_waitcnt vmcnt(0) lgkmcnt(0); s_barrier

  // Main loop: 31 pipelined iterations + tail.
  for (int kt = 0; kt < KIN / 64 - 1; ++kt) {
    const int cur = kt & 1;
    STAGE(cur ^ 1, kt + 1);   // next tile's loads in flight during compute
    COMPUTE(cur);
    __syncthreads();          // drains next-tile loads; prev buffer now free
  }
  COMPUTE(1);                 // tile 31 (cur = 31&1 = 1), no prefetch

  // ---- fused epilogue: all 5 gates of (b, h) live in this lane ----
  const int h   = nt * 32 + q * 16 + lr;
  const float bgi = bg[h];
  const float bgf = bg[HH + h];
  const float bgo = bg[2 * HH + h];
  const float bc0 = bc[2 * h];
  const float bc1 = bc[2 * h + 1];
  const float gb  = b2[0];

  float p0[16], p1[16], ga[16];
#pragma unroll
  for (int mi = 0; mi < 4; ++mi)
#pragma unroll
    for (int r = 0; r < 4; ++r) {
      p0[mi * 4 + r] = acc[mi][3][r] + bc0;
      p1[mi * 4 + r] = acc[mi][4][r] + bc1;
      ga[mi * 4 + r] = gb;
    }
  // inner MLP: k-outer so the 4 uniform weight scalars stay in SGPRs
#pragma unroll
  for (int k = 0; k < KH; ++k) {
    float w0 = W1[2 * k], w1 = W1[2 * k + 1], bk = b1[k], wk = W2[k];
#pragma unroll
    for (int e = 0; e < 16; ++e) {
      float hv = fmaf(p0[e], w0, fmaf(p1[e], w1, bk));
      hv = fmaxf(hv, 0.0f);
      ga[e] = fmaf(hv, wk, ga[e]);
    }
  }

#pragma unroll
  for (int mi = 0; mi < 4; ++mi)
#pragma unroll
    for (int r = 0; r < 4; ++r) {
      int b    = m0 + wm + mi * 16 + qd * 4 + r;
      size_t o = (size_t)b * HH + h;
      float si = 1.0f / (1.0f + __expf(-(acc[mi][0][r] + bgi)));
      float sf = 1.0f / (1.0f + __expf(-(acc[mi][1][r] + bgf)));
      float so = 1.0f / (1.0f + __expf(-(acc[mi][2][r] + bgo)));
      float cn = fmaf(sf, c_prev[o], si * ga[mi * 4 + r]);
      float e2 = __expf(2.0f * cn);          // tanh(cn) = 1 - 2/(e^{2cn}+1)
      float th = 1.0f - 2.0f / (e2 + 1.0f);
      h_next[o] = so * th;
      c_next[o] = cn;
    }
}

// ---------------------------------------------------------------------------
extern "C" void kernel_launch(void* const* d_in, const int* in_sizes, int n_in,
                              void* d_out, int out_size, void* d_ws, size_t ws_size,
                              hipStream_t stream) {
  const float* x      = (const float*)d_in[0];
  const float* h_prev = (const float*)d_in[1];
  const float* c_prev = (const float*)d_in[2];
  const float* Wg     = (const float*)d_in[3];
  const float* bg     = (const float*)d_in[4];
  const float* Wc     = (const float*)d_in[5];
  const float* bc     = (const float*)d_in[6];
  const float* W1     = (const float*)d_in[7];
  const float* b1     = (const float*)d_in[8];
  const float* W2     = (const float*)d_in[9];
  const float* b2     = (const float*)d_in[10];
  float* out = (float*)d_out;

  // workspace layout
  char* ws = (char*)d_ws;
  bf16* comb = (bf16*)ws;                                    // 16 MB
  bf16* Wb   = (bf16*)(ws + (size_t)BB * KIN * 2);           // 20 MB

  // 1. prep (concat + cast + gate-permuted, sequential-read B shuffle)
  prep<<<NCB + NWB, 256, 0, stream>>>(x, h_prev, Wg, Wc, comb, Wb);

  // 2. fused GEMM + epilogue (2-phase double-buffered pipeline)
  dim3 grid(BB / 128, NTG);
  gemm_fused<<<grid, 256, 0, stream>>>(comb, Wb, c_prev, bg, bc, W1, b1, W2,
                                       b2, out, out + (size_t)BB * HH);
}

// Round 6
// 234.426 us; speedup vs baseline: 1.5300x; 1.0500x over previous
//
#include <hip/hip_runtime.h>
#include <hip/hip_bf16.h>

// Problem constants
#define BB   4096
#define INW  1024
#define HH   1024
#define KIN  2048      // IN + H
#define NG   5120      // 3H + 2H
#define KH   32        // inner hidden
#define FPG  10        // 16-col fragments per 160-col gate-group
#define NTG  32        // number of gate-groups (= H/32)

typedef __bf16 bf16;
typedef __bf16 bf16x4 __attribute__((ext_vector_type(4)));
typedef __bf16 bf16x8 __attribute__((ext_vector_type(8)));
typedef float  floatx4 __attribute__((ext_vector_type(4)));

#define GLD16(gp, lp)                                                          \
  __builtin_amdgcn_global_load_lds(                                            \
      (__attribute__((address_space(1))) const void*)(gp),                     \
      (__attribute__((address_space(3))) void*)(lp), 16, 0, 0)

// ---------------------------------------------------------------------------
// 1. prep (unchanged — sequential-row B shuffle, coalesced comb).
//    Wb chunk layout [F][kk][lane] with F = nt*10+f: chunk = (F*64 + kk)*64 +
//    (kq*16 + s) holds B[hcol = nt*32 + (f/5)*16 + s, gate f%5]
//    [k = kk*32 + kq*8 .. +7].
// ---------------------------------------------------------------------------
#define NCB  4096      // comb blocks: BB*KIN/8 threads / 256
#define NWB  1280      // Wb blocks: 32 nt x 10 f x 4 row-quarters

__global__ __launch_bounds__(256) void prep(
    const float* __restrict__ x, const float* __restrict__ h,
    const float* __restrict__ Wg, const float* __restrict__ Wc,
    bf16* __restrict__ comb, bf16* __restrict__ Wb) {
  int tid = threadIdx.x;
  if (blockIdx.x < NCB) {              // ---- comb: concat + cast ----
    int e = (blockIdx.x * 256 + tid) * 8;
    int b = e >> 11;          // / KIN
    int c = e & (KIN - 1);
    const float* src = (c < INW) ? (x + (size_t)b * INW + c)
                                 : (h + (size_t)b * HH + (c - INW));
    float4 v0 = *(const float4*)src;
    float4 v1 = *(const float4*)(src + 4);
    bf16x8 ov;
    ov[0] = (bf16)v0.x; ov[1] = (bf16)v0.y; ov[2] = (bf16)v0.z; ov[3] = (bf16)v0.w;
    ov[4] = (bf16)v1.x; ov[5] = (bf16)v1.y; ov[6] = (bf16)v1.z; ov[7] = (bf16)v1.w;
    *(bf16x8*)(comb + e) = ov;
  } else {                             // ---- Wb: sequential-row shuffle ----
    int w   = blockIdx.x - NCB;        // [0, 1280)
    int nt  = w / 40;
    int rem = w - nt * 40;
    int f   = rem >> 2;                // fragment slot 0..9
    int rp  = rem & 3;                 // row-quarter 0..3
    int q   = f / 5;
    int g   = f - q * 5;               // gate: 0=i 1=f 2=o 3=p0 4=p1
    int kk  = tid >> 2;                // k-chunk of 32
    int kq  = tid & 3;                 // k-quad within chunk
    size_t wbase = ((size_t)(nt * FPG + f) * 64 + kk) * 64 + kq * 16;
#pragma unroll
    for (int r4 = 0; r4 < 4; ++r4) {
      int s    = rp * 4 + r4;          // row-in-fragment 0..15
      int hcol = nt * 32 + q * 16 + s;
      const float* src = (g < 3)
          ? (Wg + (size_t)(g * HH + hcol) * KIN + tid * 8)
          : (Wc + (size_t)(2 * hcol + (g - 3)) * KIN + tid * 8);
      float4 v0 = *(const float4*)src;
      float4 v1 = *(const float4*)(src + 4);
      bf16x8 ov;
      ov[0] = (bf16)v0.x; ov[1] = (bf16)v0.y; ov[2] = (bf16)v0.z; ov[3] = (bf16)v0.w;
      ov[4] = (bf16)v1.x; ov[5] = (bf16)v1.y; ov[6] = (bf16)v1.z; ov[7] = (bf16)v1.w;
      *(bf16x8*)(Wb + (wbase + s) * 8) = ov;
    }
  }
}

// ---------------------------------------------------------------------------
// 2. Fused GEMM + LSTM epilogue. R6 = R5 (2-phase double-buffered pipeline,
//    128x160 tile, BK=64, A+B via global_load_lds) + two changes:
//    (a) XCD partition refined: each XCD owns 4 EXCLUSIVE nt-panels
//        (4 x 640 KB = 2.56 MB, resident in its 4 MB L2 for the kernel's
//        whole lifetime) and 4 consecutive blocks within an XCD share one
//        m-tile across the 4 nt -> each A-tile is L2-filled ONCE per XCD
//        and served to 4 blocks. (R5 counter-match: A streamed 2x per XCD
//        = 256 MB FETCH; predicted now ~128 MB A + 20 MB B.)
//    (b) T5: s_setprio(1) around the MFMA clusters — 2 independent blocks
//        per CU at different phases gives the scheduler role diversity.
// ---------------------------------------------------------------------------
#define ASZ  8192      // A elems per buffer (16 KB)
#define BSZ  10240     // B elems per buffer (20 KB)
#define BUF  (ASZ + BSZ)

__global__ __launch_bounds__(256, 2) void gemm_fused(
    const bf16* __restrict__ A, const bf16* __restrict__ Bm,
    const float* __restrict__ c_prev, const float* __restrict__ bg,
    const float* __restrict__ bc, const float* __restrict__ W1,
    const float* __restrict__ b1, const float* __restrict__ W2,
    const float* __restrict__ b2, float* __restrict__ h_next,
    float* __restrict__ c_next) {
  __shared__ bf16 sh[2 * BUF];     // 72 KB: two {A 16K + B 20K} buffers

  const int tid  = threadIdx.x;
  const int wave = tid >> 6;
  const int lane = tid & 63;

  // XCD partition (bijective, 1024 = 8 xcd x 32 m x 4 nt):
  //   xcd owns nt in [4*xcd, 4*xcd+4)  -> B slice L2-resident (2.56 MB)
  //   within xcd, 4 consecutive blocks share one m-tile across the 4 nt
  //   -> co-resident set = 16 m x 4 nt; each A-tile filled once, read 4x.
  const int bid = blockIdx.y * gridDim.x + blockIdx.x;
  const int xcd = bid & 7;
  const int ib  = bid >> 3;          // 0..127 within XCD
  const int m0  = (ib >> 2) * 128;
  const int nt  = xcd * 4 + (ib & 3);

  const int wm = (wave >> 1) * 64;   // wave row origin in tile
  const int q  = wave & 1;           // wave col half: which 16 h's
  const int lr = lane & 15;
  const int qd = lane >> 4;

  floatx4 acc[4][5] = {};

  // Per-thread staging constants
  const int arow0 = tid >> 3;                 // A rows handled: arow0 + j*32
  const int acol  = (tid & 7);                // swizzled below per row
  const int bf20  = wave;                     // B chunks: wave + j*4

  // ---- STAGE(buf, kt): 4 A-chunks + 5 B-chunks per thread ----
#define STAGE(bb, kt)                                                          \
  {                                                                            \
    _Pragma("unroll")                                                          \
    for (int j = 0; j < 4; ++j) {                                              \
      int row = arow0 + j * 32;                                                \
      int c   = acol ^ (row & 7);                                              \
      GLD16(A + (size_t)(m0 + row) * KIN + (kt) * 64 + c * 8,                  \
            sh + (size_t)(bb) * BUF + (size_t)(j * 256 + wave * 64) * 8);      \
    }                                                                          \
    _Pragma("unroll")                                                          \
    for (int j = 0; j < 5; ++j) {                                              \
      int c20 = j * 4 + bf20;                                                  \
      int f   = c20 >> 1;                                                      \
      int ks  = c20 & 1;                                                       \
      size_t gchunk = (size_t)(nt * FPG + f) * 64 + ((kt) * 2 + ks);           \
      GLD16(Bm + (gchunk * 64 + lane) * 8,                                     \
            sh + (size_t)(bb) * BUF + ASZ +                                    \
                (size_t)(j * 256 + wave * 64) * 8);                            \
    }                                                                          \
  }

  // ---- COMPUTE(buf): 2 k-steps x 20 MFMA from buffer bb ----
#define COMPUTE(bb)                                                            \
  {                                                                            \
    const bf16* As = sh + (size_t)(bb) * BUF;                                  \
    const bf16* Bs = As + ASZ;                                                 \
    _Pragma("unroll")                                                          \
    for (int ks = 0; ks < 2; ++ks) {                                           \
      bf16x8 af[4];                                                            \
      _Pragma("unroll")                                                        \
      for (int mi = 0; mi < 4; ++mi) {                                         \
        int row  = wm + mi * 16 + lr;                                          \
        int slot = (ks * 4 + qd) ^ (lr & 7);                                   \
        af[mi] = *(const bf16x8*)&As[(row << 6) + (slot << 3)];                \
      }                                                                        \
      bf16x8 bfr[5];                                                           \
      _Pragma("unroll")                                                        \
      for (int ni = 0; ni < 5; ++ni) {                                         \
        int chunk = ((q * 5 + ni) << 1) + ks;                                  \
        bfr[ni] = *(const bf16x8*)&Bs[(chunk << 9) + (lane << 3)];             \
      }                                                                        \
      __builtin_amdgcn_s_setprio(1);                                           \
      _Pragma("unroll")                                                        \
      for (int mi = 0; mi < 4; ++mi)                                           \
        _Pragma("unroll")                                                      \
        for (int ni = 0; ni < 5; ++ni)                                         \
          acc[mi][ni] = __builtin_amdgcn_mfma_f32_16x16x32_bf16(               \
              af[mi], bfr[ni], acc[mi][ni], 0, 0, 0);                          \
      __builtin_amdgcn_s_setprio(0);                                           \
    }                                                                          \
  }

  // Prologue: stage tile 0, drain, barrier.
  STAGE(0, 0);
  __syncthreads();   // emits s_waitcnt vmcnt(0) lgkmcnt(0); s_barrier

  // Main loop: 31 pipelined iterations + tail.
  for (int kt = 0; kt < KIN / 64 - 1; ++kt) {
    const int cur = kt & 1;
    STAGE(cur ^ 1, kt + 1);   // next tile's loads in flight during compute
    COMPUTE(cur);
    __syncthreads();          // drains next-tile loads; prev buffer now free
  }
  COMPUTE(1);                 // tile 31 (cur = 31&1 = 1), no prefetch

  // ---- fused epilogue: all 5 gates of (b, h) live in this lane ----
  const int h   = nt * 32 + q * 16 + lr;
  const float bgi = bg[h];
  const float bgf = bg[HH + h];
  const float bgo = bg[2 * HH + h];
  const float bc0 = bc[2 * h];
  const float bc1 = bc[2 * h + 1];
  const float gb  = b2[0];

  float p0[16], p1[16], ga[16];
#pragma unroll
  for (int mi = 0; mi < 4; ++mi)
#pragma unroll
    for (int r = 0; r < 4; ++r) {
      p0[mi * 4 + r] = acc[mi][3][r] + bc0;
      p1[mi * 4 + r] = acc[mi][4][r] + bc1;
      ga[mi * 4 + r] = gb;
    }
  // inner MLP: k-outer so the 4 uniform weight scalars stay in SGPRs
#pragma unroll
  for (int k = 0; k < KH; ++k) {
    float w0 = W1[2 * k], w1 = W1[2 * k + 1], bk = b1[k], wk = W2[k];
#pragma unroll
    for (int e = 0; e < 16; ++e) {
      float hv = fmaf(p0[e], w0, fmaf(p1[e], w1, bk));
      hv = fmaxf(hv, 0.0f);
      ga[e] = fmaf(hv, wk, ga[e]);
    }
  }

#pragma unroll
  for (int mi = 0; mi < 4; ++mi)
#pragma unroll
    for (int r = 0; r < 4; ++r) {
      int b    = m0 + wm + mi * 16 + qd * 4 + r;
      size_t o = (size_t)b * HH + h;
      float si = 1.0f / (1.0f + __expf(-(acc[mi][0][r] + bgi)));
      float sf = 1.0f / (1.0f + __expf(-(acc[mi][1][r] + bgf)));
      float so = 1.0f / (1.0f + __expf(-(acc[mi][2][r] + bgo)));
      float cn = fmaf(sf, c_prev[o], si * ga[mi * 4 + r]);
      float e2 = __expf(2.0f * cn);          // tanh(cn) = 1 - 2/(e^{2cn}+1)
      float th = 1.0f - 2.0f / (e2 + 1.0f);
      h_next[o] = so * th;
      c_next[o] = cn;
    }
}

// ---------------------------------------------------------------------------
extern "C" void kernel_launch(void* const* d_in, const int* in_sizes, int n_in,
                              void* d_out, int out_size, void* d_ws, size_t ws_size,
                              hipStream_t stream) {
  const float* x      = (const float*)d_in[0];
  const float* h_prev = (const float*)d_in[1];
  const float* c_prev = (const float*)d_in[2];
  const float* Wg     = (const float*)d_in[3];
  const float* bg     = (const float*)d_in[4];
  const float* Wc     = (const float*)d_in[5];
  const float* bc     = (const float*)d_in[6];
  const float* W1     = (const float*)d_in[7];
  const float* b1     = (const float*)d_in[8];
  const float* W2     = (const float*)d_in[9];
  const float* b2     = (const float*)d_in[10];
  float* out = (float*)d_out;

  // workspace layout
  char* ws = (char*)d_ws;
  bf16* comb = (bf16*)ws;                                    // 16 MB
  bf16* Wb   = (bf16*)(ws + (size_t)BB * KIN * 2);           // 20 MB

  // 1. prep (concat + cast + gate-permuted, sequential-read B shuffle)
  prep<<<NCB + NWB, 256, 0, stream>>>(x, h_prev, Wg, Wc, comb, Wb);

  // 2. fused GEMM + epilogue (2-phase double-buffered pipeline)
  dim3 grid(BB / 128, NTG);
  gemm_fused<<<grid, 256, 0, stream>>>(comb, Wb, c_prev, bg, bc, W1, b1, W2,
                                       b2, out, out + (size_t)BB * HH);
}